// Round 8
// baseline (1349.715 us; speedup 1.0000x reference)
//
#include <hip/hip_runtime.h>

#define NN 500000
#define DSH 13                            // dst-local bits (supertile 8192)
#define DNPB 8192
#define NSUP 62                           // ceil(NN/8192)
#define SSH 12                            // src-slice bits (4096 nodes = 32KB hf4)
#define NSS 123                           // ceil(NN/4096)
#define NSEG (NSUP * NSS)                 // 7626
#define PT_TILE 131072                    // edges per partition block
#define SENTV (500000u << DSH)            // sentinel: src=NN, dst-local=0

typedef _Float16 hf4 __attribute__((ext_vector_type(4)));
typedef _Float16 hf2 __attribute__((ext_vector_type(2)));
typedef unsigned int u32;
typedef u32 u4v __attribute__((ext_vector_type(4)));

__device__ __forceinline__ u4v nt_load4(const u32* p) {
    return __builtin_nontemporal_load((const u4v*)p);
}

__device__ __constant__ int QB[5] = {0, 31, 62, 93, 123};   // src-quarter slice bounds

// ============================================================================
// GCN with dst-supertile (8192) x src-quarter partial aggregation.
// packed edge = (src << 13) | (dst & 8191), segment key = (dst>>13)*123 + (src>>12)
// agg block (sup,q): LDS f32 acc[4][8192], walks contiguous src-sorted range,
// writes hf4 partial; combine sums 4 partials + fused epilogue.
// ============================================================================

// -------- per-(sup,ss) histogram --------
__global__ __launch_bounds__(256) void k_bhist(const int* __restrict__ src,
                                               const int* __restrict__ dst,
                                               int* __restrict__ bcount, int ne) {
    __shared__ int lh[NSEG];
    for (int i = threadIdx.x; i < NSEG; i += 256) lh[i] = 0;
    __syncthreads();
    int ne4 = ne >> 2;
    for (int i = blockIdx.x * 256 + threadIdx.x; i < ne4; i += gridDim.x * 256) {
        int4 d = ((const int4*)dst)[i];
        int4 s = ((const int4*)src)[i];
        atomicAdd(&lh[(d.x >> DSH) * NSS + ((unsigned)s.x >> SSH)], 1);
        atomicAdd(&lh[(d.y >> DSH) * NSS + ((unsigned)s.y >> SSH)], 1);
        atomicAdd(&lh[(d.z >> DSH) * NSS + ((unsigned)s.z >> SSH)], 1);
        atomicAdd(&lh[(d.w >> DSH) * NSS + ((unsigned)s.w >> SSH)], 1);
    }
    if (blockIdx.x == 0) {
        for (int k = (ne & ~3) + threadIdx.x; k < ne; k += 256)
            atomicAdd(&lh[(dst[k] >> DSH) * NSS + ((unsigned)src[k] >> SSH)], 1);
    }
    __syncthreads();
    for (int i = threadIdx.x; i < NSEG; i += 256)
        if (lh[i]) atomicAdd(&bcount[i], lh[i]);
}

// -------- scan NSEG counts (pad x4); init cursors; zero sentinel rows --------
__global__ __launch_bounds__(1024) void k_bscan(const int* __restrict__ bcount,
                                                int* __restrict__ bbase,
                                                int* __restrict__ cur,
                                                hf4* __restrict__ g4,
                                                hf2* __restrict__ g3) {
    __shared__ int sh[1024];
    int t = threadIdx.x;
    int v[8];
    int tot = 0;
    int i0 = t * 8;
    #pragma unroll
    for (int j = 0; j < 8; ++j) {
        int idx = i0 + j;
        int c = (idx < NSEG) ? ((bcount[idx] + 3) & ~3) : 0;
        v[j] = c;
        tot += c;
    }
    sh[t] = tot;
    __syncthreads();
    for (int o = 1; o < 1024; o <<= 1) {
        int a = (t >= o) ? sh[t - o] : 0;
        __syncthreads();
        sh[t] += a;
        __syncthreads();
    }
    int o = sh[t] - tot;
    #pragma unroll
    for (int j = 0; j < 8; ++j) {
        int idx = i0 + j;
        if (idx < NSEG) { bbase[idx] = o; cur[idx] = o; o += v[j]; }
    }
    if (t == 1023) {
        bbase[NSEG] = sh[1023];
        hf4 z4; z4.x = z4.y = z4.z = z4.w = (_Float16)0.f;
        hf2 z2; z2.x = z2.y = (_Float16)0.f;
        g4[NN] = z4; g3[NN] = z2;
    }
}

// -------- partition edges into segments (LDS hist + chunked scatter) --------
__global__ __launch_bounds__(1024) void k_part(const int* __restrict__ src,
                                               const int* __restrict__ dst,
                                               int* __restrict__ cur,
                                               u32* __restrict__ packed, int ne) {
    __shared__ int lhist[NSEG];
    __shared__ int lcur[NSEG];
    int tid = threadIdx.x;
    for (int i = tid; i < NSEG; i += 1024) lhist[i] = 0;
    __syncthreads();
    int t0 = blockIdx.x * PT_TILE;
    int t1 = t0 + PT_TILE; if (t1 > ne) t1 = ne;
    for (int e = t0 + tid * 4; e < t1; e += 4096) {
        if (e + 3 < t1) {
            int4 d = *(const int4*)(dst + e);
            int4 s = *(const int4*)(src + e);
            atomicAdd(&lhist[(d.x >> DSH) * NSS + ((unsigned)s.x >> SSH)], 1);
            atomicAdd(&lhist[(d.y >> DSH) * NSS + ((unsigned)s.y >> SSH)], 1);
            atomicAdd(&lhist[(d.z >> DSH) * NSS + ((unsigned)s.z >> SSH)], 1);
            atomicAdd(&lhist[(d.w >> DSH) * NSS + ((unsigned)s.w >> SSH)], 1);
        } else {
            for (int k = e; k < t1; ++k)
                atomicAdd(&lhist[(dst[k] >> DSH) * NSS + ((unsigned)src[k] >> SSH)], 1);
        }
    }
    __syncthreads();
    for (int i = tid; i < NSEG; i += 1024) {
        int c = lhist[i];
        lcur[i] = c ? atomicAdd(&cur[i], c) : 0;
    }
    __syncthreads();
    for (int e = t0 + tid * 4; e < t1; e += 4096) {
        if (e + 3 < t1) {
            int4 d = *(const int4*)(dst + e);
            int4 s = *(const int4*)(src + e);
            int key, p;
            key = (d.x >> DSH) * NSS + ((unsigned)s.x >> SSH);
            p = atomicAdd(&lcur[key], 1); packed[p] = ((u32)s.x << DSH) | ((u32)d.x & (DNPB - 1));
            key = (d.y >> DSH) * NSS + ((unsigned)s.y >> SSH);
            p = atomicAdd(&lcur[key], 1); packed[p] = ((u32)s.y << DSH) | ((u32)d.y & (DNPB - 1));
            key = (d.z >> DSH) * NSS + ((unsigned)s.z >> SSH);
            p = atomicAdd(&lcur[key], 1); packed[p] = ((u32)s.z << DSH) | ((u32)d.z & (DNPB - 1));
            key = (d.w >> DSH) * NSS + ((unsigned)s.w >> SSH);
            p = atomicAdd(&lcur[key], 1); packed[p] = ((u32)s.w << DSH) | ((u32)d.w & (DNPB - 1));
        } else {
            for (int k = e; k < t1; ++k) {
                int dd = dst[k], ss = src[k];
                int key = (dd >> DSH) * NSS + ((unsigned)ss >> SSH);
                int p = atomicAdd(&lcur[key], 1);
                packed[p] = ((u32)ss << DSH) | ((u32)dd & (DNPB - 1));
            }
        }
    }
}

// -------- fill padding slots with sentinel --------
__global__ __launch_bounds__(1024) void k_pad(const int* __restrict__ cur,
                                              const int* __restrict__ bbase,
                                              u32* __restrict__ packed) {
    int s = blockIdx.x * 1024 + threadIdx.x;
    if (s < NSEG) {
        int e = cur[s], e1 = bbase[s + 1];
        for (; e < e1; ++e) packed[e] = SENTV;
    }
}

// -------- degree -> dis, one block per supertile --------
__global__ __launch_bounds__(1024) void k_deg(const int* __restrict__ bbase,
                                              const u32* __restrict__ packed,
                                              float* __restrict__ dis) {
    __shared__ int cnt[DNPB];
    int tid = threadIdx.x, sup = blockIdx.x;
    #pragma unroll
    for (int j = 0; j < 8; ++j) cnt[tid + j * 1024] = 0;
    __syncthreads();
    int e0 = bbase[sup * NSS], e1 = bbase[(sup + 1) * NSS];
    for (int e = e0 + (tid << 2); e < e1; e += 4096) {
        u4v p = nt_load4(packed + e);
        if (p.x != SENTV) atomicAdd(&cnt[p.x & (DNPB - 1)], 1);
        if (p.y != SENTV) atomicAdd(&cnt[p.y & (DNPB - 1)], 1);
        if (p.z != SENTV) atomicAdd(&cnt[p.z & (DNPB - 1)], 1);
        if (p.w != SENTV) atomicAdd(&cnt[p.w & (DNPB - 1)], 1);
    }
    __syncthreads();
    int i0 = sup << DSH;
    #pragma unroll
    for (int j = 0; j < 8; ++j) {
        int k = tid + j * 1024;
        int i = i0 + k;
        if (i < NN) dis[i] = rsqrtf((float)cnt[k] + 1.0f);
    }
}

// -------- g1 = hf4( dis * (x @ W1) ), wave per row --------
__global__ __launch_bounds__(256) void k_xw(const float* __restrict__ x,
                                            const float* __restrict__ W1,
                                            const float* __restrict__ dis,
                                            hf4* __restrict__ g, int n) {
    __shared__ float4 sW[128];
    int tid = threadIdx.x;
    if (tid < 128) sW[tid] = ((const float4*)W1)[tid];
    __syncthreads();
    int wave = tid >> 6, lane = tid & 63;
    int row = blockIdx.x * 4 + wave;
    if (row >= n) return;
    float2 xv = ((const float2*)(x + (size_t)row * 128))[lane];
    float4 w0 = sW[2 * lane], w1 = sW[2 * lane + 1];
    float a0 = xv.x * w0.x + xv.y * w1.x;
    float a1 = xv.x * w0.y + xv.y * w1.y;
    float a2 = xv.x * w0.z + xv.y * w1.z;
    float a3 = xv.x * w0.w + xv.y * w1.w;
    for (int off = 32; off; off >>= 1) {
        a0 += __shfl_xor(a0, off);
        a1 += __shfl_xor(a1, off);
        a2 += __shfl_xor(a2, off);
        a3 += __shfl_xor(a3, off);
    }
    if (lane == 0) {
        float dv = dis[row];
        hf4 o;
        o.x = (_Float16)(dv * a0); o.y = (_Float16)(dv * a1);
        o.z = (_Float16)(dv * a2); o.w = (_Float16)(dv * a3);
        g[row] = o;
    }
}

#define ACC4(v, nd)                                   \
    unsafeAtomicAdd(&acc[0][nd], (float)(v).x);       \
    unsafeAtomicAdd(&acc[1][nd], (float)(v).y);       \
    unsafeAtomicAdd(&acc[2][nd], (float)(v).z);       \
    unsafeAtomicAdd(&acc[3][nd], (float)(v).w);

// -------- 4-feat partial aggregation: block = (sup*4 + quarter) --------
__global__ __launch_bounds__(1024) void k_aggP(const int* __restrict__ bbase,
                                               const u32* __restrict__ packed,
                                               const hf4* __restrict__ gin,
                                               hf4* __restrict__ part) {
    __shared__ float acc[4][DNPB];              // 128 KB
    int tid = threadIdx.x, b = blockIdx.x;
    int sup = b >> 2, q = b & 3;
    #pragma unroll
    for (int j = 0; j < 8; ++j) {
        int k = tid + j * 1024;
        acc[0][k] = 0.f; acc[1][k] = 0.f; acc[2][k] = 0.f; acc[3][k] = 0.f;
    }
    __syncthreads();
    int e0 = bbase[sup * NSS + QB[q]];
    int e1 = bbase[sup * NSS + QB[q + 1]];
    for (int e = e0 + (tid << 2); e < e1; e += 4096) {
        u4v p = nt_load4(packed + e);
        hf4 v0 = gin[p.x >> DSH];
        hf4 v1 = gin[p.y >> DSH];
        hf4 v2 = gin[p.z >> DSH];
        hf4 v3 = gin[p.w >> DSH];
        ACC4(v0, p.x & (DNPB - 1));
        ACC4(v1, p.y & (DNPB - 1));
        ACC4(v2, p.z & (DNPB - 1));
        ACC4(v3, p.w & (DNPB - 1));
    }
    __syncthreads();
    size_t pb = (size_t)b * DNPB;
    #pragma unroll
    for (int j = 0; j < 8; ++j) {
        int k = tid + j * 1024;
        hf4 o;
        o.x = (_Float16)acc[0][k]; o.y = (_Float16)acc[1][k];
        o.z = (_Float16)acc[2][k]; o.w = (_Float16)acc[3][k];
        part[pb + k] = o;
    }
}

// -------- 2-feat partial aggregation (layer 3) --------
__global__ __launch_bounds__(1024) void k_aggP2(const int* __restrict__ bbase,
                                                const u32* __restrict__ packed,
                                                const hf2* __restrict__ gin,
                                                hf2* __restrict__ part) {
    __shared__ float acc[2][DNPB];              // 64 KB
    int tid = threadIdx.x, b = blockIdx.x;
    int sup = b >> 2, q = b & 3;
    #pragma unroll
    for (int j = 0; j < 8; ++j) {
        int k = tid + j * 1024;
        acc[0][k] = 0.f; acc[1][k] = 0.f;
    }
    __syncthreads();
    int e0 = bbase[sup * NSS + QB[q]];
    int e1 = bbase[sup * NSS + QB[q + 1]];
    for (int e = e0 + (tid << 2); e < e1; e += 4096) {
        u4v p = nt_load4(packed + e);
        hf2 v0 = gin[p.x >> DSH];
        hf2 v1 = gin[p.y >> DSH];
        hf2 v2 = gin[p.z >> DSH];
        hf2 v3 = gin[p.w >> DSH];
        int nd;
        nd = p.x & (DNPB - 1);
        unsafeAtomicAdd(&acc[0][nd], (float)v0.x); unsafeAtomicAdd(&acc[1][nd], (float)v0.y);
        nd = p.y & (DNPB - 1);
        unsafeAtomicAdd(&acc[0][nd], (float)v1.x); unsafeAtomicAdd(&acc[1][nd], (float)v1.y);
        nd = p.z & (DNPB - 1);
        unsafeAtomicAdd(&acc[0][nd], (float)v2.x); unsafeAtomicAdd(&acc[1][nd], (float)v2.y);
        nd = p.w & (DNPB - 1);
        unsafeAtomicAdd(&acc[0][nd], (float)v3.x); unsafeAtomicAdd(&acc[1][nd], (float)v3.y);
    }
    __syncthreads();
    size_t pb = (size_t)b * DNPB;
    #pragma unroll
    for (int j = 0; j < 8; ++j) {
        int k = tid + j * 1024;
        hf2 o;
        o.x = (_Float16)acc[0][k]; o.y = (_Float16)acc[1][k];
        part[pb + k] = o;
    }
}

// -------- combine 4 partials + epilogue, 4->4 (writes g4 in place) --------
__global__ __launch_bounds__(1024) void k_comb44(const hf4* __restrict__ part,
                                                 hf4* __restrict__ g4,
                                                 const float* __restrict__ dis,
                                                 const float* __restrict__ bias,
                                                 const float* __restrict__ W) {
    int i = blockIdx.x * 1024 + threadIdx.x;
    if (i >= NN) return;
    int sup = i >> DSH, loc = i & (DNPB - 1);
    size_t base = (size_t)(sup * 4) * DNPB + loc;
    hf4 p0 = part[base], p1 = part[base + DNPB], p2 = part[base + 2 * DNPB], p3 = part[base + 3 * DNPB];
    float s0 = (float)p0.x + (float)p1.x + (float)p2.x + (float)p3.x;
    float s1 = (float)p0.y + (float)p1.y + (float)p2.y + (float)p3.y;
    float s2 = (float)p0.z + (float)p1.z + (float)p2.z + (float)p3.z;
    float s3 = (float)p0.w + (float)p1.w + (float)p2.w + (float)p3.w;
    float dv = dis[i];
    hf4 gs = g4[i];
    float h0 = tanhf(dv * (s0 + (float)gs.x) + bias[0]);
    float h1 = tanhf(dv * (s1 + (float)gs.y) + bias[1]);
    float h2 = tanhf(dv * (s2 + (float)gs.z) + bias[2]);
    float h3 = tanhf(dv * (s3 + (float)gs.w) + bias[3]);
    hf4 o;
    o.x = (_Float16)(dv * (h0 * W[0] + h1 * W[4] + h2 * W[8]  + h3 * W[12]));
    o.y = (_Float16)(dv * (h0 * W[1] + h1 * W[5] + h2 * W[9]  + h3 * W[13]));
    o.z = (_Float16)(dv * (h0 * W[2] + h1 * W[6] + h2 * W[10] + h3 * W[14]));
    o.w = (_Float16)(dv * (h0 * W[3] + h1 * W[7] + h2 * W[11] + h3 * W[15]));
    g4[i] = o;
}

// -------- combine + epilogue, 4->2 (writes g3) --------
__global__ __launch_bounds__(1024) void k_comb42(const hf4* __restrict__ part,
                                                 const hf4* __restrict__ g4,
                                                 hf2* __restrict__ g3,
                                                 const float* __restrict__ dis,
                                                 const float* __restrict__ bias,
                                                 const float* __restrict__ W) {
    int i = blockIdx.x * 1024 + threadIdx.x;
    if (i >= NN) return;
    int sup = i >> DSH, loc = i & (DNPB - 1);
    size_t base = (size_t)(sup * 4) * DNPB + loc;
    hf4 p0 = part[base], p1 = part[base + DNPB], p2 = part[base + 2 * DNPB], p3 = part[base + 3 * DNPB];
    float s0 = (float)p0.x + (float)p1.x + (float)p2.x + (float)p3.x;
    float s1 = (float)p0.y + (float)p1.y + (float)p2.y + (float)p3.y;
    float s2 = (float)p0.z + (float)p1.z + (float)p2.z + (float)p3.z;
    float s3 = (float)p0.w + (float)p1.w + (float)p2.w + (float)p3.w;
    float dv = dis[i];
    hf4 gs = g4[i];
    float h0 = tanhf(dv * (s0 + (float)gs.x) + bias[0]);
    float h1 = tanhf(dv * (s1 + (float)gs.y) + bias[1]);
    float h2 = tanhf(dv * (s2 + (float)gs.z) + bias[2]);
    float h3 = tanhf(dv * (s3 + (float)gs.w) + bias[3]);
    hf2 o;
    o.x = (_Float16)(dv * (h0 * W[0] + h1 * W[2] + h2 * W[4] + h3 * W[6]));
    o.y = (_Float16)(dv * (h0 * W[1] + h1 * W[3] + h2 * W[5] + h3 * W[7]));
    g3[i] = o;
}

// -------- combine + final classifier --------
__global__ __launch_bounds__(1024) void k_comb2out(const hf2* __restrict__ part,
                                                   const hf2* __restrict__ g3,
                                                   const float* __restrict__ dis,
                                                   const float* __restrict__ b3,
                                                   const float* __restrict__ Wc,
                                                   const float* __restrict__ bc,
                                                   float4* __restrict__ out,
                                                   float2* __restrict__ hout) {
    int i = blockIdx.x * 1024 + threadIdx.x;
    if (i >= NN) return;
    int sup = i >> DSH, loc = i & (DNPB - 1);
    size_t base = (size_t)(sup * 4) * DNPB + loc;
    hf2 p0 = part[base], p1 = part[base + DNPB], p2 = part[base + 2 * DNPB], p3 = part[base + 3 * DNPB];
    float s0 = (float)p0.x + (float)p1.x + (float)p2.x + (float)p3.x;
    float s1 = (float)p0.y + (float)p1.y + (float)p2.y + (float)p3.y;
    float dv = dis[i];
    hf2 gs = g3[i];
    float h0 = tanhf(dv * (s0 + (float)gs.x) + b3[0]);
    float h1 = tanhf(dv * (s1 + (float)gs.y) + b3[1]);
    float4 o;
    o.x = h0 * Wc[0] + h1 * Wc[4] + bc[0];
    o.y = h0 * Wc[1] + h1 * Wc[5] + bc[1];
    o.z = h0 * Wc[2] + h1 * Wc[6] + bc[2];
    o.w = h0 * Wc[3] + h1 * Wc[7] + bc[3];
    out[i] = o;
    hout[i] = make_float2(h0, h1);
}

extern "C" void kernel_launch(void* const* d_in, const int* in_sizes, int n_in,
                              void* d_out, int out_size, void* d_ws, size_t ws_size,
                              hipStream_t stream) {
    const float* x  = (const float*)d_in[0];
    const int*   ei = (const int*)d_in[1];
    const float* W1 = (const float*)d_in[2];
    const float* b1 = (const float*)d_in[3];
    const float* W2 = (const float*)d_in[4];
    const float* b2 = (const float*)d_in[5];
    const float* W3 = (const float*)d_in[6];
    const float* b3 = (const float*)d_in[7];
    const float* Wc = (const float*)d_in[8];
    const float* bc = (const float*)d_in[9];

    const int n  = NN;
    const int ne = in_sizes[1] / 2;
    const int* src  = ei;
    const int* dstp = ei + ne;

    const int cap = ne + 4 * NSEG;

    char* base = (char*)d_ws;
    u32*   packed = (u32*)base;     base += ((size_t)cap * 4 + 15) & ~15ull;
    float* dis    = (float*)base;   base += (size_t)n * 4;
    hf4*   g4     = (hf4*)base;     base += ((size_t)n + 1) * 8;
    hf2*   g3     = (hf2*)base;     base += (((size_t)n + 1) * 4 + 15) & ~15ull;
    hf4*   part   = (hf4*)base;     base += (size_t)NSUP * 4 * DNPB * 8;   // 16.25 MB
    int*   bcount = (int*)base;     base += (NSEG + 1) * 4;
    int*   bbase  = (int*)base;     base += (NSEG + 1) * 4;
    int*   cur    = (int*)base;

    float4* out4  = (float4*)d_out;
    float2* hout2 = (float2*)((float*)d_out + 4 * (size_t)n);

    const int NPBLK = 248;                     // NSUP*4
    const int combb = (n + 1023) / 1024;

    hipMemsetAsync(bcount, 0, (NSEG + 1) * 4, stream);
    k_bhist<<<256, 256, 0, stream>>>(src, dstp, bcount, ne);
    k_bscan<<<1, 1024, 0, stream>>>(bcount, bbase, cur, g4, g3);
    k_part<<<(ne + PT_TILE - 1) / PT_TILE, 1024, 0, stream>>>(src, dstp, cur, packed, ne);
    k_pad<<<(NSEG + 1023) / 1024, 1024, 0, stream>>>(cur, bbase, packed);
    k_deg<<<NSUP, 1024, 0, stream>>>(bbase, packed, dis);
    k_xw<<<(n + 3) / 4, 256, 0, stream>>>(x, W1, dis, g4, n);

    // layer 1
    k_aggP<<<NPBLK, 1024, 0, stream>>>(bbase, packed, g4, part);
    k_comb44<<<combb, 1024, 0, stream>>>(part, g4, dis, b1, W2);
    // layer 2
    k_aggP<<<NPBLK, 1024, 0, stream>>>(bbase, packed, g4, part);
    k_comb42<<<combb, 1024, 0, stream>>>(part, g4, g3, dis, b2, W3);
    // layer 3 + classifier
    k_aggP2<<<NPBLK, 1024, 0, stream>>>(bbase, packed, g3, (hf2*)part);
    k_comb2out<<<combb, 1024, 0, stream>>>((const hf2*)part, g3, dis, b3, Wc, bc,
                                           out4, hout2);
}

// Round 9
// 821.856 us; speedup vs baseline: 1.6423x; 1.6423x over previous
//
#include <hip/hip_runtime.h>

#define NN 500000
#define SH 9
#define NPB 512
#define NBUCK ((NN + NPB - 1) / NPB)      // 977
#define PT_TILE 32768
#define CAP 24576                          // LDS sort capacity (mean 16378, sigma 128)
#define SPARECAP (2 << 20)                 // overflow spare (edges)

typedef _Float16 hf4 __attribute__((ext_vector_type(4)));
typedef _Float16 hf2 __attribute__((ext_vector_type(2)));

__device__ __forceinline__ int nt_ld(const int* p) {
    return __builtin_nontemporal_load(p);
}

// ============================================================================
// CSR-pull GCN, zero atomics in per-layer passes:
//  bhist/bscan/part: bucket edges by dst>>9, packed=(src<<9)|(dst&511)
//  k_sort: per bucket, LDS counting-sort edges by dst-local; writes ssrc
//          in place + per-node cnt/off
//  k_xw:   g1 = hf4( rsqrt(cnt+1) * (x @ W1) )
//  k_pull*: 16 lanes/node, register accumulate + shfl reduce + fused epilogue
// ============================================================================

__global__ __launch_bounds__(256) void k_bhist(const int* __restrict__ dst,
                                               int* __restrict__ bcount, int ne) {
    __shared__ int lh[NBUCK];
    for (int i = threadIdx.x; i < NBUCK; i += 256) lh[i] = 0;
    __syncthreads();
    int ne4 = ne >> 2;
    for (int i = blockIdx.x * 256 + threadIdx.x; i < ne4; i += gridDim.x * 256) {
        int4 d = ((const int4*)dst)[i];
        atomicAdd(&lh[d.x >> SH], 1);
        atomicAdd(&lh[d.y >> SH], 1);
        atomicAdd(&lh[d.z >> SH], 1);
        atomicAdd(&lh[d.w >> SH], 1);
    }
    if (blockIdx.x == 0) {
        for (int k = (ne & ~3) + threadIdx.x; k < ne; k += 256)
            atomicAdd(&lh[dst[k] >> SH], 1);
    }
    __syncthreads();
    for (int i = threadIdx.x; i < NBUCK; i += 256)
        if (lh[i]) atomicAdd(&bcount[i], lh[i]);
}

__global__ __launch_bounds__(1024) void k_bscan(const int* __restrict__ bcount,
                                                int* __restrict__ bbase,
                                                int* __restrict__ pcur) {
    __shared__ int sh[1024];
    int t = threadIdx.x;
    int v = (t < NBUCK) ? bcount[t] : 0;
    sh[t] = v;
    __syncthreads();
    for (int o = 1; o < 1024; o <<= 1) {
        int a = (t >= o) ? sh[t - o] : 0;
        __syncthreads();
        sh[t] += a;
        __syncthreads();
    }
    if (t < NBUCK) {
        int excl = sh[t] - v;
        bbase[t] = excl;
        pcur[t] = excl;
        if (t == NBUCK - 1) bbase[NBUCK] = sh[t];
    }
}

__global__ __launch_bounds__(256) void k_part(const int* __restrict__ src,
                                              const int* __restrict__ dst,
                                              int* __restrict__ pcur,
                                              int* __restrict__ packed, int ne) {
    __shared__ int lhist[NBUCK];
    __shared__ int lcur[NBUCK];
    int tid = threadIdx.x;
    for (int i = tid; i < NBUCK; i += 256) lhist[i] = 0;
    __syncthreads();
    int t0 = blockIdx.x * PT_TILE;
    int t1 = t0 + PT_TILE; if (t1 > ne) t1 = ne;
    for (int e = t0 + tid * 4; e < t1; e += 1024) {
        if (e + 3 < t1) {
            int4 d = *(const int4*)(dst + e);
            atomicAdd(&lhist[d.x >> SH], 1);
            atomicAdd(&lhist[d.y >> SH], 1);
            atomicAdd(&lhist[d.z >> SH], 1);
            atomicAdd(&lhist[d.w >> SH], 1);
        } else {
            for (int k = e; k < t1; ++k) atomicAdd(&lhist[dst[k] >> SH], 1);
        }
    }
    __syncthreads();
    for (int i = tid; i < NBUCK; i += 256) {
        int c = lhist[i];
        lcur[i] = c ? atomicAdd(&pcur[i], c) : 0;
    }
    __syncthreads();
    for (int e = t0 + tid * 4; e < t1; e += 1024) {
        if (e + 3 < t1) {
            int4 d = *(const int4*)(dst + e);
            int4 s = *(const int4*)(src + e);
            int b, p;
            b = d.x >> SH; p = atomicAdd(&lcur[b], 1); packed[p] = (s.x << SH) | (d.x & (NPB - 1));
            b = d.y >> SH; p = atomicAdd(&lcur[b], 1); packed[p] = (s.y << SH) | (d.y & (NPB - 1));
            b = d.z >> SH; p = atomicAdd(&lcur[b], 1); packed[p] = (s.z << SH) | (d.z & (NPB - 1));
            b = d.w >> SH; p = atomicAdd(&lcur[b], 1); packed[p] = (s.w << SH) | (d.w & (NPB - 1));
        } else {
            for (int k = e; k < t1; ++k) {
                int dd = dst[k], ss = src[k];
                int b = dd >> SH;
                int p = atomicAdd(&lcur[b], 1);
                packed[p] = (ss << SH) | (dd & (NPB - 1));
            }
        }
    }
}

// per-bucket LDS counting sort; writes ssrc in place over packed + cnt/off
__global__ __launch_bounds__(1024) void k_sort(const int* __restrict__ bbase,
                                               int* __restrict__ packed,
                                               int* __restrict__ cnt,
                                               int* __restrict__ off,
                                               int* __restrict__ spare,
                                               int* __restrict__ spare_ctr) {
    __shared__ int scnt[NPB];
    __shared__ int scur[NPB];
    __shared__ int sbase_sh;
    __shared__ int sarr[CAP];
    int tid = threadIdx.x, b = blockIdx.x;
    int e0 = bbase[b], e1 = bbase[b + 1], m = e1 - e0;
    if (tid < NPB) scnt[tid] = 0;
    __syncthreads();
    for (int e = e0 + tid; e < e1; e += 1024)
        atomicAdd(&scnt[packed[e] & (NPB - 1)], 1);
    __syncthreads();
    if (tid < NPB) scur[tid] = scnt[tid];
    __syncthreads();
    for (int o = 1; o < NPB; o <<= 1) {
        int a = (tid < NPB && tid >= o) ? scur[tid - o] : 0;
        __syncthreads();
        if (tid < NPB) scur[tid] += a;
        __syncthreads();
    }
    int node0 = b << SH;
    if (tid < NPB) {
        int excl = scur[tid] - scnt[tid];
        int i = node0 + tid;
        if (i < NN) { cnt[i] = scnt[tid]; off[i] = e0 + excl; }
        scur[tid] = excl;
    }
    __syncthreads();
    if (m <= CAP) {
        for (int e = e0 + tid; e < e1; e += 1024) {
            int p = packed[e];
            int slot = atomicAdd(&scur[p & (NPB - 1)], 1);
            sarr[slot] = p >> SH;
        }
        __syncthreads();
        for (int k = tid; k < m; k += 1024)
            packed[e0 + k] = sarr[k];
    } else {
        if (tid == 0) sbase_sh = atomicAdd(spare_ctr, m);
        __syncthreads();
        int sb = sbase_sh;
        if (sb + m <= SPARECAP) {
            for (int k = tid; k < m; k += 1024) spare[sb + k] = packed[e0 + k];
            __syncthreads();
            for (int k = tid; k < m; k += 1024) {
                int p = spare[sb + k];
                int slot = atomicAdd(&scur[p & (NPB - 1)], 1);
                packed[e0 + slot] = p >> SH;
            }
        }
    }
}

// g1 = hf4( rsqrt(cnt+1) * (x @ W1) ), wave per row
__global__ __launch_bounds__(256) void k_xw(const float* __restrict__ x,
                                            const float* __restrict__ W1,
                                            const int* __restrict__ cnt,
                                            hf4* __restrict__ g, int n) {
    __shared__ float4 sW[128];
    int tid = threadIdx.x;
    if (tid < 128) sW[tid] = ((const float4*)W1)[tid];
    __syncthreads();
    int wave = tid >> 6, lane = tid & 63;
    int row = blockIdx.x * 4 + wave;
    if (row >= n) return;
    float2 xv = ((const float2*)(x + (size_t)row * 128))[lane];
    float4 w0 = sW[2 * lane], w1 = sW[2 * lane + 1];
    float a0 = xv.x * w0.x + xv.y * w1.x;
    float a1 = xv.x * w0.y + xv.y * w1.y;
    float a2 = xv.x * w0.z + xv.y * w1.z;
    float a3 = xv.x * w0.w + xv.y * w1.w;
    for (int off = 32; off; off >>= 1) {
        a0 += __shfl_xor(a0, off);
        a1 += __shfl_xor(a1, off);
        a2 += __shfl_xor(a2, off);
        a3 += __shfl_xor(a3, off);
    }
    if (lane == 0) {
        float dv = rsqrtf((float)cnt[row] + 1.0f);
        hf4 o;
        o.x = (_Float16)(dv * a0); o.y = (_Float16)(dv * a1);
        o.z = (_Float16)(dv * a2); o.w = (_Float16)(dv * a3);
        g[row] = o;
    }
}

// pull layer: g1(hf4) -> g2(hf4) via b1, W2
__global__ __launch_bounds__(512) void k_pull44(const int* __restrict__ off,
                                                const int* __restrict__ cnt,
                                                const int* __restrict__ ssrc,
                                                const hf4* __restrict__ gin,
                                                const float* __restrict__ bias,
                                                const float* __restrict__ W,
                                                hf4* __restrict__ gout) {
    int tid = threadIdx.x;
    int node = blockIdx.x * 32 + (tid >> 4);
    int sl = tid & 15;
    if (node >= NN) return;
    int begin = off[node], c = cnt[node];
    float a0 = 0.f, a1 = 0.f, a2 = 0.f, a3 = 0.f;
    for (int k = sl; k < c; k += 16) {
        hf4 gv = gin[nt_ld(ssrc + begin + k)];
        a0 += (float)gv.x; a1 += (float)gv.y; a2 += (float)gv.z; a3 += (float)gv.w;
    }
    for (int o = 1; o < 16; o <<= 1) {
        a0 += __shfl_xor(a0, o);
        a1 += __shfl_xor(a1, o);
        a2 += __shfl_xor(a2, o);
        a3 += __shfl_xor(a3, o);
    }
    if (sl == 0) {
        float dv = rsqrtf((float)c + 1.0f);
        hf4 gs = gin[node];
        float h0 = tanhf(dv * (a0 + (float)gs.x) + bias[0]);
        float h1 = tanhf(dv * (a1 + (float)gs.y) + bias[1]);
        float h2 = tanhf(dv * (a2 + (float)gs.z) + bias[2]);
        float h3 = tanhf(dv * (a3 + (float)gs.w) + bias[3]);
        hf4 o;
        o.x = (_Float16)(dv * (h0 * W[0] + h1 * W[4] + h2 * W[8]  + h3 * W[12]));
        o.y = (_Float16)(dv * (h0 * W[1] + h1 * W[5] + h2 * W[9]  + h3 * W[13]));
        o.z = (_Float16)(dv * (h0 * W[2] + h1 * W[6] + h2 * W[10] + h3 * W[14]));
        o.w = (_Float16)(dv * (h0 * W[3] + h1 * W[7] + h2 * W[11] + h3 * W[15]));
        gout[node] = o;
    }
}

// pull layer: g2(hf4) -> g3(hf2) via b2, W3
__global__ __launch_bounds__(512) void k_pull42(const int* __restrict__ off,
                                                const int* __restrict__ cnt,
                                                const int* __restrict__ ssrc,
                                                const hf4* __restrict__ gin,
                                                const float* __restrict__ bias,
                                                const float* __restrict__ W,
                                                hf2* __restrict__ gout) {
    int tid = threadIdx.x;
    int node = blockIdx.x * 32 + (tid >> 4);
    int sl = tid & 15;
    if (node >= NN) return;
    int begin = off[node], c = cnt[node];
    float a0 = 0.f, a1 = 0.f, a2 = 0.f, a3 = 0.f;
    for (int k = sl; k < c; k += 16) {
        hf4 gv = gin[nt_ld(ssrc + begin + k)];
        a0 += (float)gv.x; a1 += (float)gv.y; a2 += (float)gv.z; a3 += (float)gv.w;
    }
    for (int o = 1; o < 16; o <<= 1) {
        a0 += __shfl_xor(a0, o);
        a1 += __shfl_xor(a1, o);
        a2 += __shfl_xor(a2, o);
        a3 += __shfl_xor(a3, o);
    }
    if (sl == 0) {
        float dv = rsqrtf((float)c + 1.0f);
        hf4 gs = gin[node];
        float h0 = tanhf(dv * (a0 + (float)gs.x) + bias[0]);
        float h1 = tanhf(dv * (a1 + (float)gs.y) + bias[1]);
        float h2 = tanhf(dv * (a2 + (float)gs.z) + bias[2]);
        float h3 = tanhf(dv * (a3 + (float)gs.w) + bias[3]);
        hf2 o;
        o.x = (_Float16)(dv * (h0 * W[0] + h1 * W[2] + h2 * W[4] + h3 * W[6]));
        o.y = (_Float16)(dv * (h0 * W[1] + h1 * W[3] + h2 * W[5] + h3 * W[7]));
        gout[node] = o;
    }
}

// pull layer 3 + classifier
__global__ __launch_bounds__(512) void k_pull2out(const int* __restrict__ off,
                                                  const int* __restrict__ cnt,
                                                  const int* __restrict__ ssrc,
                                                  const hf2* __restrict__ gin,
                                                  const float* __restrict__ b3,
                                                  const float* __restrict__ Wc,
                                                  const float* __restrict__ bc,
                                                  float4* __restrict__ out,
                                                  float2* __restrict__ hout) {
    int tid = threadIdx.x;
    int node = blockIdx.x * 32 + (tid >> 4);
    int sl = tid & 15;
    if (node >= NN) return;
    int begin = off[node], c = cnt[node];
    float a0 = 0.f, a1 = 0.f;
    for (int k = sl; k < c; k += 16) {
        hf2 gv = gin[nt_ld(ssrc + begin + k)];
        a0 += (float)gv.x; a1 += (float)gv.y;
    }
    for (int o = 1; o < 16; o <<= 1) {
        a0 += __shfl_xor(a0, o);
        a1 += __shfl_xor(a1, o);
    }
    if (sl == 0) {
        float dv = rsqrtf((float)c + 1.0f);
        hf2 gs = gin[node];
        float h0 = tanhf(dv * (a0 + (float)gs.x) + b3[0]);
        float h1 = tanhf(dv * (a1 + (float)gs.y) + b3[1]);
        float4 o;
        o.x = h0 * Wc[0] + h1 * Wc[4] + bc[0];
        o.y = h0 * Wc[1] + h1 * Wc[5] + bc[1];
        o.z = h0 * Wc[2] + h1 * Wc[6] + bc[2];
        o.w = h0 * Wc[3] + h1 * Wc[7] + bc[3];
        out[node] = o;
        hout[node] = make_float2(h0, h1);
    }
}

extern "C" void kernel_launch(void* const* d_in, const int* in_sizes, int n_in,
                              void* d_out, int out_size, void* d_ws, size_t ws_size,
                              hipStream_t stream) {
    const float* x  = (const float*)d_in[0];
    const int*   ei = (const int*)d_in[1];
    const float* W1 = (const float*)d_in[2];
    const float* b1 = (const float*)d_in[3];
    const float* W2 = (const float*)d_in[4];
    const float* b2 = (const float*)d_in[5];
    const float* W3 = (const float*)d_in[6];
    const float* b3 = (const float*)d_in[7];
    const float* Wc = (const float*)d_in[8];
    const float* bc = (const float*)d_in[9];

    const int n  = NN;
    const int ne = in_sizes[1] / 2;
    const int* src  = ei;
    const int* dstp = ei + ne;

    // ws: packed[ne] 64MB | g1 4MB | g2 4MB | g3 2MB | cnt 2MB | off 2MB |
    //     bcount|bbase|pcur|spare_ctr (12KB, zeroed together) | spare 8MB  = ~86MB
    char* base = (char*)d_ws;
    int*   packed = (int*)base;      base += ((size_t)ne * 4 + 15) & ~15ull;
    hf4*   g1     = (hf4*)base;      base += (size_t)n * 8;
    hf4*   g2     = (hf4*)base;      base += (size_t)n * 8;
    hf2*   g3     = (hf2*)base;      base += (((size_t)n * 4) + 15) & ~15ull;
    int*   cnt    = (int*)base;      base += (size_t)n * 4;
    int*   off    = (int*)base;      base += (size_t)n * 4;
    int*   bcount = (int*)base;      base += (NBUCK + 1) * 4;
    int*   bbase  = (int*)base;      base += (NBUCK + 1) * 4;
    int*   pcur   = (int*)base;      base += (NBUCK + 1) * 4;
    int*   spare_ctr = (int*)base;   base += 16;
    int*   spare  = (int*)base;

    float4* out4  = (float4*)d_out;
    float2* hout2 = (float2*)((float*)d_out + 4 * (size_t)n);

    const size_t zbytes = (char*)spare_ctr + 4 - (char*)bcount;
    hipMemsetAsync(bcount, 0, zbytes, stream);

    k_bhist<<<512, 256, 0, stream>>>(dstp, bcount, ne);
    k_bscan<<<1, 1024, 0, stream>>>(bcount, bbase, pcur);
    k_part<<<(ne + PT_TILE - 1) / PT_TILE, 256, 0, stream>>>(src, dstp, pcur, packed, ne);
    k_sort<<<NBUCK, 1024, 0, stream>>>(bbase, packed, cnt, off, spare, spare_ctr);
    k_xw<<<(n + 3) / 4, 256, 0, stream>>>(x, W1, cnt, g1, n);
    k_pull44<<<(n + 31) / 32, 512, 0, stream>>>(off, cnt, packed, g1, b1, W2, g2);
    k_pull42<<<(n + 31) / 32, 512, 0, stream>>>(off, cnt, packed, g2, b2, W3, g3);
    k_pull2out<<<(n + 31) / 32, 512, 0, stream>>>(off, cnt, packed, g3, b3, Wc, bc,
                                                  out4, hout2);
}

// Round 10
// 812.279 us; speedup vs baseline: 1.6616x; 1.0118x over previous
//
#include <hip/hip_runtime.h>

#define NN 500000
#define SH 9
#define NPB 512
#define NBUCK ((NN + NPB - 1) / NPB)      // 977
#define PT_TILE 131072                     // edges per partition block (big tiles)
#define CAP 24576                          // LDS sort capacity (mean 16378, sigma 128)
#define SPARECAP (2 << 20)                 // overflow spare (edges)

typedef _Float16 hf4 __attribute__((ext_vector_type(4)));
typedef _Float16 hf2 __attribute__((ext_vector_type(2)));

__device__ __forceinline__ int nt_ld(const int* p) {
    return __builtin_nontemporal_load(p);
}

// ============================================================================
// CSR-pull GCN, zero atomics in per-layer passes:
//  bhist/bscan/part: bucket edges by dst>>9, packed=(src<<9)|(dst&511)
//  k_sort: per bucket, LDS counting-sort edges by dst-local; writes ssrc
//          in place + per-node cnt/off
//  k_xw:   g1 = hf4( rsqrt(cnt+1) * (x @ W1) )
//  k_pull*: 16 lanes/node, register accumulate + shfl reduce + fused epilogue
// ============================================================================

__global__ __launch_bounds__(256) void k_bhist(const int* __restrict__ dst,
                                               int* __restrict__ bcount, int ne) {
    __shared__ int lh[NBUCK];
    for (int i = threadIdx.x; i < NBUCK; i += 256) lh[i] = 0;
    __syncthreads();
    int ne4 = ne >> 2;
    for (int i = blockIdx.x * 256 + threadIdx.x; i < ne4; i += gridDim.x * 256) {
        int4 d = ((const int4*)dst)[i];
        atomicAdd(&lh[d.x >> SH], 1);
        atomicAdd(&lh[d.y >> SH], 1);
        atomicAdd(&lh[d.z >> SH], 1);
        atomicAdd(&lh[d.w >> SH], 1);
    }
    if (blockIdx.x == 0) {
        for (int k = (ne & ~3) + threadIdx.x; k < ne; k += 256)
            atomicAdd(&lh[dst[k] >> SH], 1);
    }
    __syncthreads();
    for (int i = threadIdx.x; i < NBUCK; i += 256)
        if (lh[i]) atomicAdd(&bcount[i], lh[i]);
}

__global__ __launch_bounds__(1024) void k_bscan(const int* __restrict__ bcount,
                                                int* __restrict__ bbase,
                                                int* __restrict__ pcur) {
    __shared__ int sh[1024];
    int t = threadIdx.x;
    int v = (t < NBUCK) ? bcount[t] : 0;
    sh[t] = v;
    __syncthreads();
    for (int o = 1; o < 1024; o <<= 1) {
        int a = (t >= o) ? sh[t - o] : 0;
        __syncthreads();
        sh[t] += a;
        __syncthreads();
    }
    if (t < NBUCK) {
        int excl = sh[t] - v;
        bbase[t] = excl;
        pcur[t] = excl;
        if (t == NBUCK - 1) bbase[NBUCK] = sh[t];
    }
}

__global__ __launch_bounds__(1024) void k_part(const int* __restrict__ src,
                                               const int* __restrict__ dst,
                                               int* __restrict__ pcur,
                                               int* __restrict__ packed, int ne) {
    __shared__ int lhist[NBUCK];
    __shared__ int lcur[NBUCK];
    int tid = threadIdx.x;
    for (int i = tid; i < NBUCK; i += 1024) lhist[i] = 0;
    __syncthreads();
    int t0 = blockIdx.x * PT_TILE;
    int t1 = t0 + PT_TILE; if (t1 > ne) t1 = ne;
    for (int e = t0 + tid * 4; e < t1; e += 4096) {
        if (e + 3 < t1) {
            int4 d = *(const int4*)(dst + e);
            atomicAdd(&lhist[d.x >> SH], 1);
            atomicAdd(&lhist[d.y >> SH], 1);
            atomicAdd(&lhist[d.z >> SH], 1);
            atomicAdd(&lhist[d.w >> SH], 1);
        } else {
            for (int k = e; k < t1; ++k) atomicAdd(&lhist[dst[k] >> SH], 1);
        }
    }
    __syncthreads();
    for (int i = tid; i < NBUCK; i += 1024) {
        int c = lhist[i];
        lcur[i] = c ? atomicAdd(&pcur[i], c) : 0;
    }
    __syncthreads();
    for (int e = t0 + tid * 4; e < t1; e += 4096) {
        if (e + 3 < t1) {
            int4 d = *(const int4*)(dst + e);
            int4 s = *(const int4*)(src + e);
            int b, p;
            b = d.x >> SH; p = atomicAdd(&lcur[b], 1); packed[p] = (s.x << SH) | (d.x & (NPB - 1));
            b = d.y >> SH; p = atomicAdd(&lcur[b], 1); packed[p] = (s.y << SH) | (d.y & (NPB - 1));
            b = d.z >> SH; p = atomicAdd(&lcur[b], 1); packed[p] = (s.z << SH) | (d.z & (NPB - 1));
            b = d.w >> SH; p = atomicAdd(&lcur[b], 1); packed[p] = (s.w << SH) | (d.w & (NPB - 1));
        } else {
            for (int k = e; k < t1; ++k) {
                int dd = dst[k], ss = src[k];
                int b = dd >> SH;
                int p = atomicAdd(&lcur[b], 1);
                packed[p] = (ss << SH) | (dd & (NPB - 1));
            }
        }
    }
}

// per-bucket LDS counting sort; writes ssrc in place over packed + cnt/off
__global__ __launch_bounds__(1024) void k_sort(const int* __restrict__ bbase,
                                               int* __restrict__ packed,
                                               int* __restrict__ cnt,
                                               int* __restrict__ off,
                                               int* __restrict__ spare,
                                               int* __restrict__ spare_ctr) {
    __shared__ int scnt[NPB];
    __shared__ int scur[NPB];
    __shared__ int sbase_sh;
    __shared__ int sarr[CAP];
    int tid = threadIdx.x, b = blockIdx.x;
    int e0 = bbase[b], e1 = bbase[b + 1], m = e1 - e0;
    if (tid < NPB) scnt[tid] = 0;
    __syncthreads();
    for (int e = e0 + tid; e < e1; e += 1024)
        atomicAdd(&scnt[packed[e] & (NPB - 1)], 1);
    __syncthreads();
    if (tid < NPB) scur[tid] = scnt[tid];
    __syncthreads();
    for (int o = 1; o < NPB; o <<= 1) {
        int a = (tid < NPB && tid >= o) ? scur[tid - o] : 0;
        __syncthreads();
        if (tid < NPB) scur[tid] += a;
        __syncthreads();
    }
    int node0 = b << SH;
    if (tid < NPB) {
        int excl = scur[tid] - scnt[tid];
        int i = node0 + tid;
        if (i < NN) { cnt[i] = scnt[tid]; off[i] = e0 + excl; }
        scur[tid] = excl;
    }
    __syncthreads();
    if (m <= CAP) {
        for (int e = e0 + tid; e < e1; e += 1024) {
            int p = packed[e];
            int slot = atomicAdd(&scur[p & (NPB - 1)], 1);
            sarr[slot] = p >> SH;
        }
        __syncthreads();
        for (int k = tid; k < m; k += 1024)
            packed[e0 + k] = sarr[k];
    } else {
        if (tid == 0) sbase_sh = atomicAdd(spare_ctr, m);
        __syncthreads();
        int sb = sbase_sh;
        if (sb + m <= SPARECAP) {
            for (int k = tid; k < m; k += 1024) spare[sb + k] = packed[e0 + k];
            __syncthreads();
            for (int k = tid; k < m; k += 1024) {
                int p = spare[sb + k];
                int slot = atomicAdd(&scur[p & (NPB - 1)], 1);
                packed[e0 + slot] = p >> SH;
            }
        }
    }
}

// g1 = hf4( rsqrt(cnt+1) * (x @ W1) ), wave per row
__global__ __launch_bounds__(256) void k_xw(const float* __restrict__ x,
                                            const float* __restrict__ W1,
                                            const int* __restrict__ cnt,
                                            hf4* __restrict__ g, int n) {
    __shared__ float4 sW[128];
    int tid = threadIdx.x;
    if (tid < 128) sW[tid] = ((const float4*)W1)[tid];
    __syncthreads();
    int wave = tid >> 6, lane = tid & 63;
    int row = blockIdx.x * 4 + wave;
    if (row >= n) return;
    float2 xv = ((const float2*)(x + (size_t)row * 128))[lane];
    float4 w0 = sW[2 * lane], w1 = sW[2 * lane + 1];
    float a0 = xv.x * w0.x + xv.y * w1.x;
    float a1 = xv.x * w0.y + xv.y * w1.y;
    float a2 = xv.x * w0.z + xv.y * w1.z;
    float a3 = xv.x * w0.w + xv.y * w1.w;
    for (int off = 32; off; off >>= 1) {
        a0 += __shfl_xor(a0, off);
        a1 += __shfl_xor(a1, off);
        a2 += __shfl_xor(a2, off);
        a3 += __shfl_xor(a3, off);
    }
    if (lane == 0) {
        float dv = rsqrtf((float)cnt[row] + 1.0f);
        hf4 o;
        o.x = (_Float16)(dv * a0); o.y = (_Float16)(dv * a1);
        o.z = (_Float16)(dv * a2); o.w = (_Float16)(dv * a3);
        g[row] = o;
    }
}

// pull layer: g1(hf4) -> g2(hf4) via b1, W2
__global__ __launch_bounds__(512) void k_pull44(const int* __restrict__ off,
                                                const int* __restrict__ cnt,
                                                const int* __restrict__ ssrc,
                                                const hf4* __restrict__ gin,
                                                const float* __restrict__ bias,
                                                const float* __restrict__ W,
                                                hf4* __restrict__ gout) {
    int tid = threadIdx.x;
    int node = blockIdx.x * 32 + (tid >> 4);
    int sl = tid & 15;
    if (node >= NN) return;
    int begin = off[node], c = cnt[node];
    float a0 = 0.f, a1 = 0.f, a2 = 0.f, a3 = 0.f;
    for (int k = sl; k < c; k += 16) {
        hf4 gv = gin[nt_ld(ssrc + begin + k)];
        a0 += (float)gv.x; a1 += (float)gv.y; a2 += (float)gv.z; a3 += (float)gv.w;
    }
    for (int o = 1; o < 16; o <<= 1) {
        a0 += __shfl_xor(a0, o);
        a1 += __shfl_xor(a1, o);
        a2 += __shfl_xor(a2, o);
        a3 += __shfl_xor(a3, o);
    }
    if (sl == 0) {
        float dv = rsqrtf((float)c + 1.0f);
        hf4 gs = gin[node];
        float h0 = tanhf(dv * (a0 + (float)gs.x) + bias[0]);
        float h1 = tanhf(dv * (a1 + (float)gs.y) + bias[1]);
        float h2 = tanhf(dv * (a2 + (float)gs.z) + bias[2]);
        float h3 = tanhf(dv * (a3 + (float)gs.w) + bias[3]);
        hf4 o;
        o.x = (_Float16)(dv * (h0 * W[0] + h1 * W[4] + h2 * W[8]  + h3 * W[12]));
        o.y = (_Float16)(dv * (h0 * W[1] + h1 * W[5] + h2 * W[9]  + h3 * W[13]));
        o.z = (_Float16)(dv * (h0 * W[2] + h1 * W[6] + h2 * W[10] + h3 * W[14]));
        o.w = (_Float16)(dv * (h0 * W[3] + h1 * W[7] + h2 * W[11] + h3 * W[15]));
        gout[node] = o;
    }
}

// pull layer: g2(hf4) -> g3(hf2) via b2, W3
__global__ __launch_bounds__(512) void k_pull42(const int* __restrict__ off,
                                                const int* __restrict__ cnt,
                                                const int* __restrict__ ssrc,
                                                const hf4* __restrict__ gin,
                                                const float* __restrict__ bias,
                                                const float* __restrict__ W,
                                                hf2* __restrict__ gout) {
    int tid = threadIdx.x;
    int node = blockIdx.x * 32 + (tid >> 4);
    int sl = tid & 15;
    if (node >= NN) return;
    int begin = off[node], c = cnt[node];
    float a0 = 0.f, a1 = 0.f, a2 = 0.f, a3 = 0.f;
    for (int k = sl; k < c; k += 16) {
        hf4 gv = gin[nt_ld(ssrc + begin + k)];
        a0 += (float)gv.x; a1 += (float)gv.y; a2 += (float)gv.z; a3 += (float)gv.w;
    }
    for (int o = 1; o < 16; o <<= 1) {
        a0 += __shfl_xor(a0, o);
        a1 += __shfl_xor(a1, o);
        a2 += __shfl_xor(a2, o);
        a3 += __shfl_xor(a3, o);
    }
    if (sl == 0) {
        float dv = rsqrtf((float)c + 1.0f);
        hf4 gs = gin[node];
        float h0 = tanhf(dv * (a0 + (float)gs.x) + bias[0]);
        float h1 = tanhf(dv * (a1 + (float)gs.y) + bias[1]);
        float h2 = tanhf(dv * (a2 + (float)gs.z) + bias[2]);
        float h3 = tanhf(dv * (a3 + (float)gs.w) + bias[3]);
        hf2 o;
        o.x = (_Float16)(dv * (h0 * W[0] + h1 * W[2] + h2 * W[4] + h3 * W[6]));
        o.y = (_Float16)(dv * (h0 * W[1] + h1 * W[3] + h2 * W[5] + h3 * W[7]));
        gout[node] = o;
    }
}

// pull layer 3 + classifier
__global__ __launch_bounds__(512) void k_pull2out(const int* __restrict__ off,
                                                  const int* __restrict__ cnt,
                                                  const int* __restrict__ ssrc,
                                                  const hf2* __restrict__ gin,
                                                  const float* __restrict__ b3,
                                                  const float* __restrict__ Wc,
                                                  const float* __restrict__ bc,
                                                  float4* __restrict__ out,
                                                  float2* __restrict__ hout) {
    int tid = threadIdx.x;
    int node = blockIdx.x * 32 + (tid >> 4);
    int sl = tid & 15;
    if (node >= NN) return;
    int begin = off[node], c = cnt[node];
    float a0 = 0.f, a1 = 0.f;
    for (int k = sl; k < c; k += 16) {
        hf2 gv = gin[nt_ld(ssrc + begin + k)];
        a0 += (float)gv.x; a1 += (float)gv.y;
    }
    for (int o = 1; o < 16; o <<= 1) {
        a0 += __shfl_xor(a0, o);
        a1 += __shfl_xor(a1, o);
    }
    if (sl == 0) {
        float dv = rsqrtf((float)c + 1.0f);
        hf2 gs = gin[node];
        float h0 = tanhf(dv * (a0 + (float)gs.x) + b3[0]);
        float h1 = tanhf(dv * (a1 + (float)gs.y) + b3[1]);
        float4 o;
        o.x = h0 * Wc[0] + h1 * Wc[4] + bc[0];
        o.y = h0 * Wc[1] + h1 * Wc[5] + bc[1];
        o.z = h0 * Wc[2] + h1 * Wc[6] + bc[2];
        o.w = h0 * Wc[3] + h1 * Wc[7] + bc[3];
        out[node] = o;
        hout[node] = make_float2(h0, h1);
    }
}

extern "C" void kernel_launch(void* const* d_in, const int* in_sizes, int n_in,
                              void* d_out, int out_size, void* d_ws, size_t ws_size,
                              hipStream_t stream) {
    const float* x  = (const float*)d_in[0];
    const int*   ei = (const int*)d_in[1];
    const float* W1 = (const float*)d_in[2];
    const float* b1 = (const float*)d_in[3];
    const float* W2 = (const float*)d_in[4];
    const float* b2 = (const float*)d_in[5];
    const float* W3 = (const float*)d_in[6];
    const float* b3 = (const float*)d_in[7];
    const float* Wc = (const float*)d_in[8];
    const float* bc = (const float*)d_in[9];

    const int n  = NN;
    const int ne = in_sizes[1] / 2;
    const int* src  = ei;
    const int* dstp = ei + ne;

    // ws: packed[ne] 64MB | g1 4MB | g2 4MB | g3 2MB | cnt 2MB | off 2MB |
    //     bcount|bbase|pcur|spare_ctr (12KB, zeroed together) | spare 8MB  = ~86MB
    char* base = (char*)d_ws;
    int*   packed = (int*)base;      base += ((size_t)ne * 4 + 15) & ~15ull;
    hf4*   g1     = (hf4*)base;      base += (size_t)n * 8;
    hf4*   g2     = (hf4*)base;      base += (size_t)n * 8;
    hf2*   g3     = (hf2*)base;      base += (((size_t)n * 4) + 15) & ~15ull;
    int*   cnt    = (int*)base;      base += (size_t)n * 4;
    int*   off    = (int*)base;      base += (size_t)n * 4;
    int*   bcount = (int*)base;      base += (NBUCK + 1) * 4;
    int*   bbase  = (int*)base;      base += (NBUCK + 1) * 4;
    int*   pcur   = (int*)base;      base += (NBUCK + 1) * 4;
    int*   spare_ctr = (int*)base;   base += 16;
    int*   spare  = (int*)base;

    float4* out4  = (float4*)d_out;
    float2* hout2 = (float2*)((float*)d_out + 4 * (size_t)n);

    const size_t zbytes = (char*)spare_ctr + 4 - (char*)bcount;
    hipMemsetAsync(bcount, 0, zbytes, stream);

    k_bhist<<<512, 256, 0, stream>>>(dstp, bcount, ne);
    k_bscan<<<1, 1024, 0, stream>>>(bcount, bbase, pcur);
    k_part<<<(ne + PT_TILE - 1) / PT_TILE, 1024, 0, stream>>>(src, dstp, pcur, packed, ne);
    k_sort<<<NBUCK, 1024, 0, stream>>>(bbase, packed, cnt, off, spare, spare_ctr);
    k_xw<<<(n + 3) / 4, 256, 0, stream>>>(x, W1, cnt, g1, n);
    k_pull44<<<(n + 31) / 32, 512, 0, stream>>>(off, cnt, packed, g1, b1, W2, g2);
    k_pull42<<<(n + 31) / 32, 512, 0, stream>>>(off, cnt, packed, g2, b2, W3, g3);
    k_pull2out<<<(n + 31) / 32, 512, 0, stream>>>(off, cnt, packed, g3, b3, Wc, bc,
                                                  out4, hout2);
}